// Round 1
// baseline (710.596 us; speedup 1.0000x reference)
//
#include <hip/hip_runtime.h>
#include <cmath>

#define BATCH 32768
#define LEN   2048
#define NGRP  4
#define GLEN  64

__device__ __forceinline__ float fast_tanh(float x){
    float ax = fabsf(x);
    float e  = __expf(-2.f*ax);
    float r  = __fdividef(1.f - e, 1.f + e);
    return copysignf(r, x);
}
__device__ __forceinline__ float tanh2(float x){ return fast_tanh(fast_tanh(x)); }

// Kernel A: x_site conv + double tanh, fused compact gather of xm while row is L1-hot.
__global__ __launch_bounds__(256) void k_site(
    const float* __restrict__ x, const int* __restrict__ idx,
    const float* __restrict__ v1, const float* __restrict__ g1, const float* __restrict__ b1,
    float* __restrict__ xsite, float* __restrict__ xmws, int use_ws)
{
    float nrm = sqrtf(v1[0]*v1[0] + v1[1]*v1[1] + v1[2]*v1[2]);
    float s  = g1[0]/nrm;
    float w0 = v1[0]*s, w1 = v1[1]*s, w2 = v1[2]*s, bb = b1[0];

    __shared__ int sidx[256];
    sidx[threadIdx.x] = idx[threadIdx.x];
    __syncthreads();

    const int t = threadIdx.x;
    for (int rr = 0; rr < 4; ++rr){
        const int row = blockIdx.x*4 + rr;
        const float* xr  = x     + (size_t)row*LEN;
        float*       orr = xsite + (size_t)row*LEN;
        const int p0 = t*8;
        float4 a = *(const float4*)(xr + p0);
        float4 b = *(const float4*)(xr + p0 + 4);
        // compact gather while the row is L1-hot; coalesced write
        if (use_ws)
            xmws[(size_t)row*256 + t] = xr[sidx[t]];
        float in[10];
        in[0] = (p0 == 0) ? 0.f : xr[p0-1];
        in[1]=a.x; in[2]=a.y; in[3]=a.z; in[4]=a.w;
        in[5]=b.x; in[6]=b.y; in[7]=b.z; in[8]=b.w;
        in[9] = (p0 + 8 >= LEN) ? 0.f : xr[p0+8];
        float o[8];
        #pragma unroll
        for (int c = 0; c < 8; ++c)
            o[c] = tanh2(fmaf(w0, in[c], fmaf(w1, in[c+1], fmaf(w2, in[c+2], bb))));
        *(float4*)(orr + p0)     = make_float4(o[0],o[1],o[2],o[3]);
        *(float4*)(orr + p0 + 4) = make_float4(o[4],o[5],o[6],o[7]);
    }
}

// Kernel B: per-(row,group) MLP + gate + 4-channel conv(k=3) + double tanh -> x_bag.
// lane = (row_local<<2)|group; weights are wave-uniform -> scalar loads.
__global__ __launch_bounds__(128) void k_bag(
    const float* __restrict__ x, const float* __restrict__ xmws, const int* __restrict__ idx,
    const float* __restrict__ v2, const float* __restrict__ g2, const float* __restrict__ b2,
    const float* __restrict__ W1, const float* __restrict__ bl1,
    const float* __restrict__ W2, const float* __restrict__ bl2,
    const float* __restrict__ Wa, const float* __restrict__ ba,
    float* __restrict__ xbag, int use_ws)
{
    const int lane = threadIdx.x & 63;
    const int wave = threadIdx.x >> 6;
    const int rl   = lane >> 2;     // 0..15 local row
    const int g    = lane & 3;      // group
    const int row  = blockIdx.x*32 + wave*16 + rl;

    float xm[GLEN];
    if (use_ws){
        const float4* p = (const float4*)(xmws + (size_t)row*256 + g*64);
        #pragma unroll
        for (int q = 0; q < 16; ++q){
            float4 v = p[q];
            xm[4*q+0]=v.x; xm[4*q+1]=v.y; xm[4*q+2]=v.z; xm[4*q+3]=v.w;
        }
    } else {
        const float* xr = x + (size_t)row*LEN;
        #pragma unroll
        for (int k = 0; k < GLEN; ++k) xm[k] = xr[idx[g*64 + k]];
    }

    // l12 = relu(xm@W1^T + bl1) + relu(xm@W2^T + bl2)
    float l12[GLEN];
    const float4* W1v = (const float4*)W1;
    const float4* W2v = (const float4*)W2;
    #pragma unroll 2
    for (int j = 0; j < GLEN; ++j){
        float a1 = bl1[j], a2 = bl2[j];
        #pragma unroll
        for (int q = 0; q < 16; ++q){
            float4 u = W1v[j*16 + q];
            float4 w = W2v[j*16 + q];
            a1 = fmaf(xm[4*q+0],u.x, fmaf(xm[4*q+1],u.y, fmaf(xm[4*q+2],u.z, fmaf(xm[4*q+3],u.w, a1))));
            a2 = fmaf(xm[4*q+0],w.x, fmaf(xm[4*q+1],w.y, fmaf(xm[4*q+2],w.z, fmaf(xm[4*q+3],w.w, a2))));
        }
        l12[j] = fmaxf(a1, 0.f) + fmaxf(a2, 0.f);
    }

    // A = sigmoid(l12@Wa^T + ba); xmask = (A+1)*xm  (in place)
    const float4* Wav = (const float4*)Wa;
    #pragma unroll 2
    for (int j = 0; j < GLEN; ++j){
        float a = ba[j];
        #pragma unroll
        for (int q = 0; q < 16; ++q){
            float4 u = Wav[j*16 + q];
            a = fmaf(l12[4*q+0],u.x, fmaf(l12[4*q+1],u.y, fmaf(l12[4*q+2],u.z, fmaf(l12[4*q+3],u.w, a))));
        }
        float A = __fdividef(1.f, 1.f + __expf(-a));
        xm[j] = (A + 1.f) * xm[j];
    }

    // Exchange xmask across groups via LDS. Layout [wave][r][i*65 + k], row stride 260.
    // Bank: (4r + i + k) % 32 -> 2-way max on both writes and reads (free).
    __shared__ float X[2*16*260];
    float* Xw = X + wave*(16*260) + rl*260 + g*65;
    #pragma unroll
    for (int k = 0; k < GLEN; ++k) Xw[k] = xm[k];
    __syncthreads();

    // normalized w2 row for output channel o = g
    float wv[NGRP][3];
    float nn = 0.f;
    #pragma unroll
    for (int i = 0; i < NGRP; ++i)
        #pragma unroll
        for (int d = 0; d < 3; ++d){ float tv = v2[(g*NGRP + i)*3 + d]; nn += tv*tv; }
    float sc = g2[g] / sqrtf(nn);
    #pragma unroll
    for (int i = 0; i < NGRP; ++i)
        #pragma unroll
        for (int d = 0; d < 3; ++d) wv[i][d] = v2[(g*NGRP + i)*3 + d] * sc;

    float acc[GLEN];
    const float bo = b2[g];
    #pragma unroll
    for (int j = 0; j < GLEN; ++j) acc[j] = bo;
    const float* Xr = X + wave*(16*260) + rl*260;
    #pragma unroll
    for (int i = 0; i < NGRP; ++i){
        const float* c = Xr + i*65;
        float xp_ = 0.f, xc = c[0];
        #pragma unroll
        for (int j = 0; j < GLEN; ++j){
            float xn = (j < GLEN-1) ? c[j+1] : 0.f;
            acc[j] = fmaf(wv[i][0], xp_, fmaf(wv[i][1], xc, fmaf(wv[i][2], xn, acc[j])));
            xp_ = xc; xc = xn;
        }
    }

    float* ob = xbag + ((size_t)row*NGRP + g)*GLEN;
    #pragma unroll
    for (int q = 0; q < 16; ++q){
        float4 v = make_float4(tanh2(acc[4*q+0]), tanh2(acc[4*q+1]),
                               tanh2(acc[4*q+2]), tanh2(acc[4*q+3]));
        *(float4*)(ob + 4*q) = v;
    }
}

extern "C" void kernel_launch(void* const* d_in, const int* in_sizes, int n_in,
                              void* d_out, int out_size, void* d_ws, size_t ws_size,
                              hipStream_t stream) {
    const float* x   = (const float*)d_in[0];
    const int*   idx = (const int*)  d_in[1];
    const float* v1  = (const float*)d_in[2];
    const float* g1  = (const float*)d_in[3];
    const float* b1  = (const float*)d_in[4];
    const float* v2  = (const float*)d_in[5];
    const float* g2  = (const float*)d_in[6];
    const float* b2  = (const float*)d_in[7];
    const float* W1  = (const float*)d_in[8];
    const float* bl1 = (const float*)d_in[9];
    const float* W2  = (const float*)d_in[10];
    const float* bl2 = (const float*)d_in[11];
    const float* Wa  = (const float*)d_in[12];
    const float* ba  = (const float*)d_in[13];

    float* xbag  = (float*)d_out;                           // (B, 4, 64)
    float* xsite = (float*)d_out + (size_t)BATCH*NGRP*GLEN; // (B, 1, 2048)
    float* xmws  = (float*)d_ws;
    const int use_ws = (ws_size >= (size_t)BATCH*256*sizeof(float)) ? 1 : 0;

    k_site<<<BATCH/4, 256, 0, stream>>>(x, idx, v1, g1, b1, xsite, xmws, use_ws);
    k_bag <<<BATCH/32, 128, 0, stream>>>(x, xmws, idx, v2, g2, b2,
                                         W1, bl1, W2, bl2, Wa, ba, xbag, use_ws);
}